// Round 1
// baseline (461.067 us; speedup 1.0000x reference)
//
#include <hip/hip_runtime.h>
#include <stdint.h>

#define NROWS 8192
#define KDIM  8192
#define DIN   256
#define DOUT  256

typedef __attribute__((ext_vector_type(8))) short bf16x8;   // 8 bf16 in 4 VGPRs
typedef __attribute__((ext_vector_type(4))) float f32x4;

__device__ __forceinline__ unsigned short f2bf(float f) {
    union { float f; unsigned u; } v; v.f = f;
    unsigned r = v.u + 0x7FFFu + ((v.u >> 16) & 1u);   // RNE
    return (unsigned short)(r >> 16);
}

__device__ __forceinline__ void async_load16(const void* g, void* l) {
    __builtin_amdgcn_global_load_lds(
        (__attribute__((address_space(1))) void*)(void*)g,
        (__attribute__((address_space(3))) void*)l, 16, 0, 0);
}

// ---------------- kernel 1: dis[i] = rsqrt(rowsum(A)); optional A -> bf16 store ----------------
template <bool STORE>
__global__ __launch_bounds__(256) void k_rowsum(const float* __restrict__ A,
                                                float* __restrict__ dis,
                                                unsigned short* __restrict__ Abf) {
    const int wave = threadIdx.x >> 6, lane = threadIdx.x & 63;
    const int row = (blockIdx.x << 2) + wave;
    const float4* rp = (const float4*)(A + (size_t)row * KDIM);
    unsigned short* op = STORE ? (Abf + (size_t)row * KDIM) : nullptr;
    float s0 = 0.f, s1 = 0.f, s2 = 0.f, s3 = 0.f;
    #pragma unroll
    for (int it = 0; it < 32; it += 4) {
        float4 v0 = rp[(it + 0) * 64 + lane];
        float4 v1 = rp[(it + 1) * 64 + lane];
        float4 v2 = rp[(it + 2) * 64 + lane];
        float4 v3 = rp[(it + 3) * 64 + lane];
        if (STORE) {
            short4 b0, b1, b2, b3;
            b0.x = (short)f2bf(v0.x); b0.y = (short)f2bf(v0.y);
            b0.z = (short)f2bf(v0.z); b0.w = (short)f2bf(v0.w);
            b1.x = (short)f2bf(v1.x); b1.y = (short)f2bf(v1.y);
            b1.z = (short)f2bf(v1.z); b1.w = (short)f2bf(v1.w);
            b2.x = (short)f2bf(v2.x); b2.y = (short)f2bf(v2.y);
            b2.z = (short)f2bf(v2.z); b2.w = (short)f2bf(v2.w);
            b3.x = (short)f2bf(v3.x); b3.y = (short)f2bf(v3.y);
            b3.z = (short)f2bf(v3.z); b3.w = (short)f2bf(v3.w);
            *(short4*)(op + ((size_t)(it + 0) * 64 + lane) * 4) = b0;
            *(short4*)(op + ((size_t)(it + 1) * 64 + lane) * 4) = b1;
            *(short4*)(op + ((size_t)(it + 2) * 64 + lane) * 4) = b2;
            *(short4*)(op + ((size_t)(it + 3) * 64 + lane) * 4) = b3;
        }
        s0 += (v0.x + v0.y) + (v0.z + v0.w);
        s1 += (v1.x + v1.y) + (v1.z + v1.w);
        s2 += (v2.x + v2.y) + (v2.z + v2.w);
        s3 += (v3.x + v3.y) + (v3.z + v3.w);
    }
    float s = (s0 + s1) + (s2 + s3);
    #pragma unroll
    for (int off = 32; off > 0; off >>= 1) s += __shfl_down(s, off, 64);
    if (lane == 0) dis[row] = rsqrtf(s);
}

// ---------------- kernel 2: Zst[n][j] = dis[j] * (X @ W^T)[j][n]  (bf16, transposed) ----------------
__global__ __launch_bounds__(256, 2) void k_xw(const float* __restrict__ X,
                                               const float* __restrict__ W,
                                               const float* __restrict__ dis,
                                               unsigned short* __restrict__ Zst) {
    __shared__ short sX[64 * 72];     // 64 j-rows x 64 k, stride 72 (pad 8) -> 2-way banks
    __shared__ short sW[256 * 72];    // 256 n-rows x 64 k, stride 72; reused as transpose buf
    __shared__ float disS[64];
    const int tid = threadIdx.x;
    const int w = tid >> 6, lane = tid & 63, lm = lane & 15, lq = lane >> 4;
    const int j0 = blockIdx.x * 64;
    if (tid < 64) disS[tid] = dis[j0 + tid];
    f32x4 acc[4][4] = {};

    for (int s = 0; s < 4; ++s) {
        const int k0 = s * 64;
        // stage X tile (64x64 fp32 -> bf16)
        #pragma unroll
        for (int i = 0; i < 4; ++i) {
            int e = tid + i * 256;
            int row = e >> 4, c4 = e & 15;
            float4 v = *(const float4*)(X + (size_t)(j0 + row) * DIN + k0 + c4 * 4);
            short4 b; b.x = (short)f2bf(v.x); b.y = (short)f2bf(v.y);
            b.z = (short)f2bf(v.z); b.w = (short)f2bf(v.w);
            *(short4*)&sX[row * 72 + c4 * 4] = b;
        }
        // stage W tile (256x64 fp32 -> bf16), W is [n][k] row-major (= B^T form)
        #pragma unroll
        for (int i = 0; i < 16; ++i) {
            int e = tid + i * 256;
            int row = e >> 4, c4 = e & 15;
            float4 v = *(const float4*)(W + (size_t)row * DIN + k0 + c4 * 4);
            short4 b; b.x = (short)f2bf(v.x); b.y = (short)f2bf(v.y);
            b.z = (short)f2bf(v.z); b.w = (short)f2bf(v.w);
            *(short4*)&sW[row * 72 + c4 * 4] = b;
        }
        __syncthreads();
        #pragma unroll
        for (int kk = 0; kk < 2; ++kk) {
            const int koff = kk * 32 + lq * 8;
            bf16x8 a[4], b[4];
            #pragma unroll
            for (int mt = 0; mt < 4; ++mt)
                a[mt] = *(const bf16x8*)&sX[(mt * 16 + lm) * 72 + koff];
            #pragma unroll
            for (int nt = 0; nt < 4; ++nt)
                b[nt] = *(const bf16x8*)&sW[(w * 64 + nt * 16 + lm) * 72 + koff];
            #pragma unroll
            for (int mt = 0; mt < 4; ++mt)
                #pragma unroll
                for (int nt = 0; nt < 4; ++nt)
                    acc[mt][nt] = __builtin_amdgcn_mfma_f32_16x16x32_bf16(
                        a[mt], b[nt], acc[mt][nt], 0, 0, 0);
        }
        __syncthreads();
    }

    // transpose through LDS (reuse sW as T[n][jl], stride 72), scale by dis[j], store bf16
    #pragma unroll
    for (int mt = 0; mt < 4; ++mt)
        #pragma unroll
        for (int nt = 0; nt < 4; ++nt)
            #pragma unroll
            for (int r = 0; r < 4; ++r) {
                int jl = mt * 16 + lq * 4 + r;          // C/D: row = quad*4 + reg
                int n  = w * 64 + nt * 16 + lm;         // C/D: col = lane&15
                float v = acc[mt][nt][r] * disS[jl];
                sW[n * 72 + jl] = (short)f2bf(v);
            }
    __syncthreads();
    #pragma unroll
    for (int it = 0; it < 8; ++it) {
        int e = tid + it * 256;                 // 256 rows x 8 chunks
        int n = e >> 3, ch = e & 7;
        bf16x8 val = *(const bf16x8*)&sW[n * 72 + ch * 8];
        *(bf16x8*)(Zst + (size_t)n * NROWS + j0 + ch * 8) = val;
    }
}

// ---------------- kernel 3a (fast path): both operands bf16, pure global_load_lds staging ----------------
// BM=64, BN=256 (full), BK=64, SPLITK=4 -> 512 blocks, 2 blocks/CU.
__global__ __launch_bounds__(256, 2) void k_gemm_bf(const unsigned short* __restrict__ Abf,
                                                    const unsigned short* __restrict__ Zst,
                                                    const float* __restrict__ dis,
                                                    float* __restrict__ out) {
    __shared__ short sA[64 * 64];     // packed, XOR-swizzled (global_load_lds)
    __shared__ short sB[256 * 64];    // 4 wave-quarters, packed, XOR-swizzled
    __shared__ float disS[64];
    const int tid = threadIdx.x;
    const int w = tid >> 6, lane = tid & 63, lm = lane & 15, lq = lane >> 4;
    const int m0 = blockIdx.x * 64;
    const int split = blockIdx.y;
    const int kbase = split * 2048;
    if (tid < 64) disS[tid] = dis[m0 + tid];
    f32x4 acc[4][4] = {};
    short* sBw = &sB[w * 4096];
    short* sAw = &sA[w * 1024];       // wave stages 16 A-rows
    // global-side XOR swizzle: LDS slot (row, sc) holds k-chunk c = sc ^ (row&7)
    const int swz_c = (lane & 7) ^ (lane >> 3);

    for (int s = 0; s < 32; ++s) {
        const int k0 = kbase + s * 64;
        // B: wave stages its own 64 n-rows (8 x 16B per lane)
        const unsigned short* gB =
            Zst + (size_t)(w * 64 + (lane >> 3)) * KDIM + k0 + swz_c * 8;
        #pragma unroll
        for (int i = 0; i < 8; ++i)
            async_load16(gB + (size_t)i * 8 * KDIM, &sBw[i * 512]);
        // A: wave stages 16 m-rows (2 x 16B per lane), same swizzle
        const unsigned short* gA =
            Abf + (size_t)(m0 + w * 16 + (lane >> 3)) * KDIM + k0 + swz_c * 8;
        #pragma unroll
        for (int i = 0; i < 2; ++i)
            async_load16(gA + (size_t)i * 8 * KDIM, &sAw[i * 512]);
        __syncthreads();   // compiler emits vmcnt/lgkmcnt drain here
        #pragma unroll
        for (int kk = 0; kk < 2; ++kk) {
            const int cb = kk * 4 + lq;               // k-chunk index 0..7
            const int sc = cb ^ (lm & 7);             // undo swizzle (row&7 == lm&7)
            bf16x8 a[4], b[4];
            #pragma unroll
            for (int mt = 0; mt < 4; ++mt)
                a[mt] = *(const bf16x8*)&sA[(mt * 16 + lm) * 64 + sc * 8];
            #pragma unroll
            for (int nt = 0; nt < 4; ++nt)
                b[nt] = *(const bf16x8*)&sBw[(nt * 16 + lm) * 64 + sc * 8];
            #pragma unroll
            for (int mt = 0; mt < 4; ++mt)
                #pragma unroll
                for (int nt = 0; nt < 4; ++nt)
                    acc[mt][nt] = __builtin_amdgcn_mfma_f32_16x16x32_bf16(
                        a[mt], b[nt], acc[mt][nt], 0, 0, 0);
        }
        __syncthreads();
    }

    // epilogue: scale by dis[i]; split-K partial store
    #pragma unroll
    for (int mt = 0; mt < 4; ++mt)
        #pragma unroll
        for (int nt = 0; nt < 4; ++nt) {
            int col = w * 64 + nt * 16 + lm;
            #pragma unroll
            for (int r = 0; r < 4; ++r) {
                int rl = mt * 16 + lq * 4 + r;
                float v = acc[mt][nt][r] * disS[rl];
                out[(size_t)split * (NROWS * DOUT) + (size_t)(m0 + rl) * DOUT + col] = v;
            }
        }
}

// ---------------- kernel 3b (fallback): fp32 A with VALU convert ----------------
template <bool ATOMIC>
__global__ __launch_bounds__(256, 2) void k_gemm(const float* __restrict__ A,
                                                 const unsigned short* __restrict__ Zst,
                                                 const float* __restrict__ dis,
                                                 float* __restrict__ out) {
    __shared__ short sA[64 * 72];
    __shared__ short sB[256 * 64];
    __shared__ float disS[64];
    const int tid = threadIdx.x;
    const int w = tid >> 6, lane = tid & 63, lm = lane & 15, lq = lane >> 4;
    const int m0 = blockIdx.x * 64;
    const int split = blockIdx.y;
    const int kbase = split * 2048;
    if (tid < 64) disS[tid] = dis[m0 + tid];
    f32x4 acc[4][4] = {};
    short* sBw = &sB[w * 4096];
    const int arow = tid >> 4, ac4 = tid & 15;
    const int swz_c = (lane & 7) ^ (lane >> 3);

    for (int s = 0; s < 32; ++s) {
        const int k0 = kbase + s * 64;
        const unsigned short* gB =
            Zst + (size_t)(w * 64 + (lane >> 3)) * KDIM + k0 + swz_c * 8;
        #pragma unroll
        for (int i = 0; i < 8; ++i)
            async_load16(gB + (size_t)i * 8 * KDIM, &sBw[i * 512]);
        #pragma unroll
        for (int i = 0; i < 4; ++i) {
            int row = arow + i * 16;
            float4 v = *(const float4*)(A + (size_t)(m0 + row) * KDIM + k0 + ac4 * 4);
            short4 b; b.x = (short)f2bf(v.x); b.y = (short)f2bf(v.y);
            b.z = (short)f2bf(v.z); b.w = (short)f2bf(v.w);
            *(short4*)&sA[row * 72 + ac4 * 4] = b;
        }
        __syncthreads();
        #pragma unroll
        for (int kk = 0; kk < 2; ++kk) {
            const int koff = kk * 32 + lq * 8;
            const int cb = kk * 4 + lq;
            bf16x8 a[4], b[4];
            #pragma unroll
            for (int mt = 0; mt < 4; ++mt)
                a[mt] = *(const bf16x8*)&sA[(mt * 16 + lm) * 72 + koff];
            #pragma unroll
            for (int nt = 0; nt < 4; ++nt) {
                int nl = nt * 16 + lm;
                int scb = cb ^ (lm & 7);
                b[nt] = *(const bf16x8*)&sBw[nl * 64 + scb * 8];
            }
            #pragma unroll
            for (int mt = 0; mt < 4; ++mt)
                #pragma unroll
                for (int nt = 0; nt < 4; ++nt)
                    acc[mt][nt] = __builtin_amdgcn_mfma_f32_16x16x32_bf16(
                        a[mt], b[nt], acc[mt][nt], 0, 0, 0);
        }
        __syncthreads();
    }

    #pragma unroll
    for (int mt = 0; mt < 4; ++mt)
        #pragma unroll
        for (int nt = 0; nt < 4; ++nt) {
            int col = w * 64 + nt * 16 + lm;
            #pragma unroll
            for (int r = 0; r < 4; ++r) {
                int rl = mt * 16 + lq * 4 + r;
                float v = acc[mt][nt][r] * disS[rl];
                if (ATOMIC) {
                    atomicAdd(out + (size_t)(m0 + rl) * DOUT + col, v);
                } else {
                    out[(size_t)split * (NROWS * DOUT) + (size_t)(m0 + rl) * DOUT + col] = v;
                }
            }
        }
}

// ---------------- kernel 4: reduce 4 split-K partials ----------------
__global__ __launch_bounds__(256) void k_reduce(const float4* __restrict__ p,
                                                float4* __restrict__ out) {
    const size_t i = (size_t)blockIdx.x * 256 + threadIdx.x;       // < 524288
    const size_t stride = (size_t)NROWS * DOUT / 4;
    float4 a = p[i], b = p[i + stride], c = p[i + 2 * stride], d = p[i + 3 * stride];
    float4 r;
    r.x = (a.x + b.x) + (c.x + d.x);
    r.y = (a.y + b.y) + (c.y + d.y);
    r.z = (a.z + b.z) + (c.z + d.z);
    r.w = (a.w + b.w) + (c.w + d.w);
    out[i] = r;
}

extern "C" void kernel_launch(void* const* d_in, const int* in_sizes, int n_in,
                              void* d_out, int out_size, void* d_ws, size_t ws_size,
                              hipStream_t stream) {
    const float* X = (const float*)d_in[0];           // input [8192,256]
    const float* A = (const float*)d_in[1];           // adjacency [8192,8192]
    const float* W = (const float*)d_in[2];           // W [256,256]
    float* out = (float*)d_out;
    char* ws = (char*)d_ws;
    float* dis = (float*)ws;                                        // 32 KB
    unsigned short* Zst = (unsigned short*)(ws + 32768);            // 4 MB, [256][8192] bf16
    float* part = (float*)(ws + 32768 + 4194304);                   // 32 MB (4 splits)
    unsigned short* Abf = (unsigned short*)(ws + 32768 + 4194304 + 33554432);  // 128 MB
    const size_t need_mid  = 32768 + 4194304 + 4ull * NROWS * DOUT * sizeof(float);
    const size_t need_full = need_mid + (size_t)NROWS * KDIM * sizeof(unsigned short);

    if (ws_size >= need_full) {
        // fast path: pre-convert A to bf16 during rowsum; pure-DMA GEMM staging
        k_rowsum<true><<<NROWS / 4, 256, 0, stream>>>(A, dis, Abf);
        k_xw<<<NROWS / 64, 256, 0, stream>>>(X, W, dis, Zst);
        k_gemm_bf<<<dim3(NROWS / 64, 4), 256, 0, stream>>>(Abf, Zst, dis, part);
        k_reduce<<<(NROWS * DOUT / 4) / 256, 256, 0, stream>>>((const float4*)part,
                                                               (float4*)out);
    } else if (ws_size >= need_mid) {
        k_rowsum<false><<<NROWS / 4, 256, 0, stream>>>(A, dis, nullptr);
        k_xw<<<NROWS / 64, 256, 0, stream>>>(X, W, dis, Zst);
        k_gemm<false><<<dim3(NROWS / 64, 4), 256, 0, stream>>>(A, Zst, dis, part);
        k_reduce<<<(NROWS * DOUT / 4) / 256, 256, 0, stream>>>((const float4*)part,
                                                               (float4*)out);
    } else {
        k_rowsum<false><<<NROWS / 4, 256, 0, stream>>>(A, dis, nullptr);
        k_xw<<<NROWS / 64, 256, 0, stream>>>(X, W, dis, Zst);
        hipMemsetAsync(d_out, 0, (size_t)out_size * sizeof(float), stream);
        k_gemm<true><<<dim3(NROWS / 64, 4), 256, 0, stream>>>(A, Zst, dis, out);
    }
}

// Round 2
// 448.891 us; speedup vs baseline: 1.0271x; 1.0271x over previous
//
#include <hip/hip_runtime.h>
#include <stdint.h>

#define NROWS 8192
#define KDIM  8192
#define DIN   256
#define DOUT  256

typedef __attribute__((ext_vector_type(8))) short bf16x8;   // 8 bf16 in 4 VGPRs
typedef __attribute__((ext_vector_type(4))) float f32x4;

__device__ __forceinline__ unsigned short f2bf(float f) {
    union { float f; unsigned u; } v; v.f = f;
    unsigned r = v.u + 0x7FFFu + ((v.u >> 16) & 1u);   // RNE
    return (unsigned short)(r >> 16);
}

__device__ __forceinline__ void async_load16(const void* g, void* l) {
    __builtin_amdgcn_global_load_lds(
        (__attribute__((address_space(1))) void*)(void*)g,
        (__attribute__((address_space(3))) void*)l, 16, 0, 0);
}

// ---------------- kernel 1: dis[i] = rsqrt(rowsum(A)) ----------------
__global__ __launch_bounds__(256) void k_rowsum(const float* __restrict__ A,
                                                float* __restrict__ dis) {
    const int wave = threadIdx.x >> 6, lane = threadIdx.x & 63;
    const int row = (blockIdx.x << 2) + wave;
    const float4* rp = (const float4*)(A + (size_t)row * KDIM);
    float s0 = 0.f, s1 = 0.f, s2 = 0.f, s3 = 0.f;
    #pragma unroll
    for (int it = 0; it < 32; it += 4) {
        float4 v0 = rp[(it + 0) * 64 + lane];
        float4 v1 = rp[(it + 1) * 64 + lane];
        float4 v2 = rp[(it + 2) * 64 + lane];
        float4 v3 = rp[(it + 3) * 64 + lane];
        s0 += (v0.x + v0.y) + (v0.z + v0.w);
        s1 += (v1.x + v1.y) + (v1.z + v1.w);
        s2 += (v2.x + v2.y) + (v2.z + v2.w);
        s3 += (v3.x + v3.y) + (v3.z + v3.w);
    }
    float s = (s0 + s1) + (s2 + s3);
    #pragma unroll
    for (int off = 32; off > 0; off >>= 1) s += __shfl_down(s, off, 64);
    if (lane == 0) dis[row] = rsqrtf(s);
}

// ---------------- kernel 2: Zst[n][j] = dis[j] * (X @ W^T)[j][n]  (bf16, transposed) ----------------
__global__ __launch_bounds__(256, 2) void k_xw(const float* __restrict__ X,
                                               const float* __restrict__ W,
                                               const float* __restrict__ dis,
                                               unsigned short* __restrict__ Zst) {
    __shared__ short sX[64 * 72];     // 64 j-rows x 64 k, stride 72 (pad 8)
    __shared__ short sW[256 * 72];    // 256 n-rows x 64 k; reused as transpose buf
    __shared__ float disS[64];
    const int tid = threadIdx.x;
    const int w = tid >> 6, lane = tid & 63, lm = lane & 15, lq = lane >> 4;
    const int j0 = blockIdx.x * 64;
    if (tid < 64) disS[tid] = dis[j0 + tid];
    f32x4 acc[4][4] = {};

    for (int s = 0; s < 4; ++s) {
        const int k0 = s * 64;
        #pragma unroll
        for (int i = 0; i < 4; ++i) {
            int e = tid + i * 256;
            int row = e >> 4, c4 = e & 15;
            float4 v = *(const float4*)(X + (size_t)(j0 + row) * DIN + k0 + c4 * 4);
            short4 b; b.x = (short)f2bf(v.x); b.y = (short)f2bf(v.y);
            b.z = (short)f2bf(v.z); b.w = (short)f2bf(v.w);
            *(short4*)&sX[row * 72 + c4 * 4] = b;
        }
        #pragma unroll
        for (int i = 0; i < 16; ++i) {
            int e = tid + i * 256;
            int row = e >> 4, c4 = e & 15;
            float4 v = *(const float4*)(W + (size_t)row * DIN + k0 + c4 * 4);
            short4 b; b.x = (short)f2bf(v.x); b.y = (short)f2bf(v.y);
            b.z = (short)f2bf(v.z); b.w = (short)f2bf(v.w);
            *(short4*)&sW[row * 72 + c4 * 4] = b;
        }
        __syncthreads();
        #pragma unroll
        for (int kk = 0; kk < 2; ++kk) {
            const int koff = kk * 32 + lq * 8;
            bf16x8 a[4], b[4];
            #pragma unroll
            for (int mt = 0; mt < 4; ++mt)
                a[mt] = *(const bf16x8*)&sX[(mt * 16 + lm) * 72 + koff];
            #pragma unroll
            for (int nt = 0; nt < 4; ++nt)
                b[nt] = *(const bf16x8*)&sW[(w * 64 + nt * 16 + lm) * 72 + koff];
            #pragma unroll
            for (int mt = 0; mt < 4; ++mt)
                #pragma unroll
                for (int nt = 0; nt < 4; ++nt)
                    acc[mt][nt] = __builtin_amdgcn_mfma_f32_16x16x32_bf16(
                        a[mt], b[nt], acc[mt][nt], 0, 0, 0);
        }
        __syncthreads();
    }

    #pragma unroll
    for (int mt = 0; mt < 4; ++mt)
        #pragma unroll
        for (int nt = 0; nt < 4; ++nt)
            #pragma unroll
            for (int r = 0; r < 4; ++r) {
                int jl = mt * 16 + lq * 4 + r;          // C/D: row = quad*4 + reg
                int n  = w * 64 + nt * 16 + lm;         // C/D: col = lane&15
                float v = acc[mt][nt][r] * disS[jl];
                sW[n * 72 + jl] = (short)f2bf(v);
            }
    __syncthreads();
    #pragma unroll
    for (int it = 0; it < 8; ++it) {
        int e = tid + it * 256;
        int n = e >> 3, ch = e & 7;
        bf16x8 val = *(const bf16x8*)&sW[n * 72 + ch * 8];
        *(bf16x8*)(Zst + (size_t)n * NROWS + j0 + ch * 8) = val;
    }
}

// ---------------- kernel 3: out[i][o] (+)= dis[i] * sum_j A[i][j] * Zst[o][j] ----------------
// BM=128, BN=256 (full), BK=64, SPLITK=4 -> 256 blocks x 512 threads, 1 block/CU.
// 2-phase double-buffered: issue stage(t+1) BEFORE compute(t); one barrier/step.
// B: global_load_lds with XOR-chunk swizzle (linear LDS dest + pre-swizzled source).
// A: fp32 global->reg (issued first), cvt+ds_write AFTER compute (overlapped).
template <bool ATOMIC>
__global__ __launch_bounds__(512, 2) void k_gemm2(const float* __restrict__ A,
                                                  const unsigned short* __restrict__ Zst,
                                                  const float* __restrict__ dis,
                                                  float* __restrict__ out) {
    __shared__ short sA[2][128 * 72];   // padded stride 72 -> conflict-free reads
    __shared__ short sB[2][256 * 64];   // packed, XOR-swizzled chunks
    __shared__ float disS[128];
    const int tid = threadIdx.x;
    const int w = tid >> 6, lane = tid & 63, lm = lane & 15, lq = lane >> 4;
    const int wm = w >> 2, wn = w & 3;           // 2M x 4N wave grid
    const int m0 = blockIdx.x * 128;
    const int split = blockIdx.y;
    const int kbase = split * 2048;               // 32 K-steps of 64
    if (tid < 128) disS[tid] = dis[m0 + tid];
    f32x4 acc[4][4] = {};
    // swizzle: LDS slot (row, sc) holds k-chunk c = sc ^ (row&7); row&7 == lane>>3 at stage
    const int swz_c = (lane & 7) ^ (lane >> 3);
    // A-stage geometry: thread covers (row = tid>>4 + i*32, c16 = tid&15), 4 float4 loads
    const int arow = tid >> 4, ac = tid & 15;
    float4 va[4];

#define LOAD_A(K0)                                                                   \
    do {                                                                             \
        _Pragma("unroll")                                                            \
        for (int i = 0; i < 4; ++i)                                                  \
            va[i] = *(const float4*)(A + (size_t)(m0 + arow + i * 32) * KDIM + (K0) + ac * 4); \
    } while (0)

#define WRITE_A(BUF)                                                                 \
    do {                                                                             \
        _Pragma("unroll")                                                            \
        for (int i = 0; i < 4; ++i) {                                                \
            short4 b; b.x = (short)f2bf(va[i].x); b.y = (short)f2bf(va[i].y);        \
            b.z = (short)f2bf(va[i].z); b.w = (short)f2bf(va[i].w);                  \
            *(short4*)&sA[BUF][(arow + i * 32) * 72 + ac * 4] = b;                   \
        }                                                                            \
    } while (0)

#define STAGE_B(BUF, K0)                                                             \
    do {                                                                             \
        const unsigned short* gB =                                                   \
            Zst + (size_t)(w * 32 + (lane >> 3)) * KDIM + (K0) + swz_c * 8;          \
        short* dst = &sB[BUF][w * 2048];                                             \
        _Pragma("unroll")                                                            \
        for (int i = 0; i < 4; ++i)                                                  \
            async_load16(gB + (size_t)i * 8 * KDIM, dst + i * 512);                  \
    } while (0)

#define COMPUTE(BUF)                                                                 \
    do {                                                                             \
        _Pragma("unroll")                                                            \
        for (int kk = 0; kk < 2; ++kk) {                                             \
            const int sc = (kk * 4 + lq) ^ (lm & 7);                                 \
            bf16x8 a[4], b[4];                                                       \
            _Pragma("unroll")                                                        \
            for (int mt = 0; mt < 4; ++mt)                                           \
                a[mt] = *(const bf16x8*)&sA[BUF][(wm * 64 + mt * 16 + lm) * 72 + kk * 32 + lq * 8]; \
            _Pragma("unroll")                                                        \
            for (int nt = 0; nt < 4; ++nt)                                           \
                b[nt] = *(const bf16x8*)&sB[BUF][(wn * 64 + nt * 16 + lm) * 64 + sc * 8]; \
            _Pragma("unroll")                                                        \
            for (int mt = 0; mt < 4; ++mt)                                           \
                _Pragma("unroll")                                                    \
                for (int nt = 0; nt < 4; ++nt)                                       \
                    acc[mt][nt] = __builtin_amdgcn_mfma_f32_16x16x32_bf16(           \
                        a[mt], b[nt], acc[mt][nt], 0, 0, 0);                         \
        }                                                                            \
    } while (0)

    // prologue: stage tile 0
    LOAD_A(kbase);
    STAGE_B(0, kbase);
    WRITE_A(0);
    __syncthreads();

    int cur = 0;
    for (int s = 0; s < 31; ++s) {
        const int kn = kbase + (s + 1) * 64;
        LOAD_A(kn);            // oldest vmem: A fp32 -> regs
        STAGE_B(cur ^ 1, kn);  // async DMA into other buffer
        COMPUTE(cur);          // ds_read + 32 MFMA/wave (loads in flight underneath)
        WRITE_A(cur ^ 1);      // waits counted vmcnt for va only; B still in flight
        __syncthreads();       // drains vmcnt+lgkm: next tile fully in LDS
        cur ^= 1;
    }
    COMPUTE(cur);

#undef LOAD_A
#undef WRITE_A
#undef STAGE_B
#undef COMPUTE

    // epilogue: scale by dis[i]; split-K partial store (or atomic accumulate)
    #pragma unroll
    for (int mt = 0; mt < 4; ++mt)
        #pragma unroll
        for (int nt = 0; nt < 4; ++nt) {
            int col = wn * 64 + nt * 16 + lm;
            #pragma unroll
            for (int r = 0; r < 4; ++r) {
                int rl = wm * 64 + mt * 16 + lq * 4 + r;
                float v = acc[mt][nt][r] * disS[rl];
                if (ATOMIC) {
                    atomicAdd(out + (size_t)(m0 + rl) * DOUT + col, v);
                } else {
                    out[(size_t)split * (NROWS * DOUT) + (size_t)(m0 + rl) * DOUT + col] = v;
                }
            }
        }
}

// ---------------- kernel 4: reduce 4 split-K partials ----------------
__global__ __launch_bounds__(256) void k_reduce(const float4* __restrict__ p,
                                                float4* __restrict__ out) {
    const size_t i = (size_t)blockIdx.x * 256 + threadIdx.x;
    const size_t stride = (size_t)NROWS * DOUT / 4;
    float4 a = p[i], b = p[i + stride], c = p[i + 2 * stride], d = p[i + 3 * stride];
    float4 r;
    r.x = (a.x + b.x) + (c.x + d.x);
    r.y = (a.y + b.y) + (c.y + d.y);
    r.z = (a.z + b.z) + (c.z + d.z);
    r.w = (a.w + b.w) + (c.w + d.w);
    out[i] = r;
}

extern "C" void kernel_launch(void* const* d_in, const int* in_sizes, int n_in,
                              void* d_out, int out_size, void* d_ws, size_t ws_size,
                              hipStream_t stream) {
    const float* X = (const float*)d_in[0];           // input [8192,256]
    const float* A = (const float*)d_in[1];           // adjacency [8192,8192]
    const float* W = (const float*)d_in[2];           // W [256,256]
    float* out = (float*)d_out;
    char* ws = (char*)d_ws;
    float* dis = (float*)ws;                                        // 32 KB
    unsigned short* Zst = (unsigned short*)(ws + 32768);            // 4 MB, [256][8192] bf16
    float* part = (float*)(ws + 32768 + 4194304);                   // 32 MB (4 splits)
    const size_t need = 32768 + 4194304 + 4ull * NROWS * DOUT * sizeof(float);

    k_rowsum<<<NROWS / 4, 256, 0, stream>>>(A, dis);
    k_xw<<<NROWS / 64, 256, 0, stream>>>(X, W, dis, Zst);
    if (ws_size >= need) {
        k_gemm2<false><<<dim3(NROWS / 128, 4), 512, 0, stream>>>(A, Zst, dis, part);
        k_reduce<<<(NROWS * DOUT / 4) / 256, 256, 0, stream>>>((const float4*)part,
                                                               (float4*)out);
    } else {
        hipMemsetAsync(d_out, 0, (size_t)out_size * sizeof(float), stream);
        k_gemm2<true><<<dim3(NROWS / 128, 4), 512, 0, stream>>>(A, Zst, dis, out);
    }
}